// Round 8
// baseline (148.375 us; speedup 1.0000x reference)
//
#include <hip/hip_runtime.h>
#include <hip/hip_bf16.h>
#include <cstdint>
#include <cstddef>

#define BB 64
#define SS 2048
#define HH 768
#define LAM 0.0f
#define NEGV -1e30f

// ===== ROUND-4 STRUCTURE EXACTLY; kernel A launched 4x as a timing probe =====
// (A is idempotent: same inputs -> same scores. dur - dur_r4 = 3*A + 3 nodes.)

// ---------------- Kernel A: scores[b,s] = dot(hidden[b,s,:], w_align[H:2H]) ---
__global__ void scores_kernel(const float* __restrict__ hidden,
                              const float* __restrict__ token_mask,
                              const float* __restrict__ w_align,
                              float* __restrict__ scores) {
    int row = blockIdx.x * 4 + (threadIdx.x >> 6);   // 4 waves per block
    int lane = threadIdx.x & 63;
    float m = token_mask[(size_t)row * HH];          // broadcast scalar per row
    if (m == 0.0f) {
        if (lane == 0) scores[row] = NEGV;
        return;
    }
    const float* hrow = hidden + (size_t)row * HH;
    const float* w2 = w_align + HH;
    float acc = 0.f;
#pragma unroll
    for (int r = 0; r < 3; ++r) {
        int idx = r * 256 + lane * 4;
        float4 h = *reinterpret_cast<const float4*>(hrow + idx);
        float4 w = *reinterpret_cast<const float4*>(w2 + idx);
        acc += h.x * w.x + h.y * w.y + h.z * w.z + h.w * w.w;
    }
#pragma unroll
    for (int off = 32; off >= 1; off >>= 1) acc += __shfl_xor(acc, off);
    if (lane == 0) scores[row] = acc;
}

// ---------------- Kernel B: one block per batch row (round-4 fused) -----------
__global__ __launch_bounds__(768, 1) void tau_pool_kernel(
        const float* __restrict__ hidden,
        const float* __restrict__ pooled_tokens,
        const float* __restrict__ w_align,
        const float* __restrict__ b_align,
        const float* __restrict__ scores,
        float* __restrict__ out) {
    __shared__ int   s_idx[SS];
    __shared__ float s_p[SS];
    __shared__ int   s_cnt;

    const int b = blockIdx.x;
    const int t = threadIdx.x;
    const int lane = t & 63;
    const int wv = t >> 6;

    if (wv == 0) {
        // --- dotP = dot(pooled_tokens[b], w_align[:H]) + b0 ---
        const float* pt = pooled_tokens + b * HH;
        float dp = 0.f;
#pragma unroll
        for (int i = 0; i < 3; ++i) {
            int idx = i * 256 + lane * 4;
            float4 a = *reinterpret_cast<const float4*>(pt + idx);
            float4 w = *reinterpret_cast<const float4*>(w_align + idx);
            dp += a.x * w.x + a.y * w.y + a.z * w.z + a.w * w.w;
        }
#pragma unroll
        for (int off = 32; off >= 1; off >>= 1) dp += __shfl_xor(dp, off);
        dp += b_align[0];

        // --- load scores (NEGV sentinel == invalid) ---
        const float* sc = scores + b * SS;
        float z[32];
#pragma unroll
        for (int i = 0; i < 8; ++i) {
            float4 v = *reinterpret_cast<const float4*>(sc + i * 256 + lane * 4);
            z[i * 4 + 0] = (v.x > -1e29f) ? v.x + dp : NEGV;
            z[i * 4 + 1] = (v.y > -1e29f) ? v.y + dp : NEGV;
            z[i * 4 + 2] = (v.z > -1e29f) ? v.z + dp : NEGV;
            z[i * 4 + 3] = (v.w > -1e29f) ? v.w + dp : NEGV;
        }

        // --- zmax over valid ---
        float mx = z[0];
#pragma unroll
        for (int i = 1; i < 32; ++i) mx = fmaxf(mx, z[i]);
#pragma unroll
        for (int off = 32; off >= 1; off >>= 1) mx = fmaxf(mx, __shfl_xor(mx, off));
#pragma unroll
        for (int i = 0; i < 32; ++i) z[i] -= mx;

        // --- Newton on f(tau) = sum(max(z-tau,0)) - 1 ---
        float tau = -1.0f;
#pragma unroll 1
        for (int it = 0; it < 50; ++it) {
            float a = 0.f, c = 0.f;
#pragma unroll
            for (int i = 0; i < 32; ++i) {
                bool g = z[i] > tau;
                a += g ? z[i] : 0.f;
                c += g ? 1.f : 0.f;
            }
#pragma unroll
            for (int off = 32; off >= 1; off >>= 1) {
                a += __shfl_xor(a, off);
                c += __shfl_xor(c, off);
            }
            float tn = (a - 1.f + LAM) / c;
            if (tn == tau) break;      // wave-uniform
            tau = tn;
        }

        // --- probs: write coalesced float4, compact support into LDS ---
        const float inv = 1.f / (1.f - LAM);
        float p[32];
#pragma unroll
        for (int i = 0; i < 32; ++i) p[i] = fmaxf((z[i] - tau) * inv, 0.f);
        float* po = out + BB * HH + b * SS;
#pragma unroll
        for (int i = 0; i < 8; ++i) {
            float4 v = make_float4(p[i * 4 + 0], p[i * 4 + 1], p[i * 4 + 2], p[i * 4 + 3]);
            *reinterpret_cast<float4*>(po + i * 256 + lane * 4) = v;
        }

        int cnt = 0;
#pragma unroll
        for (int i = 0; i < 8; ++i) {
#pragma unroll
            for (int c = 0; c < 4; ++c) {
                float pv = p[i * 4 + c];
                unsigned long long m = __ballot(pv > 0.f);
                if (pv > 0.f) {
                    int pos = cnt + (int)__popcll(m & ((1ull << lane) - 1ull));
                    s_idx[pos] = i * 256 + lane * 4 + c;
                    s_p[pos] = pv;
                }
                cnt += (int)__popcll(m);
            }
        }
        if (lane == 0) s_cnt = cnt;
    }
    __syncthreads();

    // --- pooled[b,h]: all 12 waves, thread t <-> column h=t, 4 rows in flight -
    const int cnt = s_cnt;
    const float* hb = hidden + (size_t)b * SS * HH;
    float acc = 0.f;
#pragma unroll 1
    for (int j = 0; j < cnt; j += 4) {
        int   i0 = s_idx[j];
        float p0 = s_p[j];
        int   i1 = (j + 1 < cnt) ? s_idx[j + 1] : 0;
        float p1 = (j + 1 < cnt) ? s_p[j + 1] : 0.f;
        int   i2 = (j + 2 < cnt) ? s_idx[j + 2] : 0;
        float p2 = (j + 2 < cnt) ? s_p[j + 2] : 0.f;
        int   i3 = (j + 3 < cnt) ? s_idx[j + 3] : 0;
        float p3 = (j + 3 < cnt) ? s_p[j + 3] : 0.f;
        float h0 = hb[(size_t)i0 * HH + t];
        float h1 = hb[(size_t)i1 * HH + t];
        float h2 = hb[(size_t)i2 * HH + t];
        float h3 = hb[(size_t)i3 * HH + t];
        acc += p0 * h0 + p1 * h1 + p2 * h2 + p3 * h3;
    }
    out[b * HH + t] = acc;
}

extern "C" void kernel_launch(void* const* d_in, const int* in_sizes, int n_in,
                              void* d_out, int out_size, void* d_ws, size_t ws_size,
                              hipStream_t stream) {
    const float* hidden        = (const float*)d_in[0];
    const float* token_mask    = (const float*)d_in[1];
    const float* pooled_tokens = (const float*)d_in[2];
    const float* w_align       = (const float*)d_in[3];
    const float* b_align       = (const float*)d_in[4];
    float* out = (float*)d_out;

    float* scores_ws;
    if (ws_size >= (size_t)BB * SS * sizeof(float)) {
        scores_ws = (float*)d_ws;
    } else {
        scores_ws = out + BB * HH;
    }

    // TIMING PROBE: launch A 4x (idempotent). A_time = (dur - dur_r4 - eps)/3.
    for (int rep = 0; rep < 4; ++rep) {
        scores_kernel<<<dim3((BB * SS) / 4), dim3(256), 0, stream>>>(
            hidden, token_mask, w_align, scores_ws);
    }

    tau_pool_kernel<<<dim3(BB), dim3(768), 0, stream>>>(
        hidden, pooled_tokens, w_align, b_align, scores_ws, out);
}

// Round 10
// 54.876 us; speedup vs baseline: 2.7038x; 2.7038x over previous
//
#include <hip/hip_runtime.h>
#include <hip/hip_bf16.h>
#include <cstdint>
#include <cstddef>

#define BB 64
#define SS 2048
#define HH 768
#define LAM 0.0f
#define NEGV -1e30f

typedef float floatv4 __attribute__((ext_vector_type(4)));  // clang-native vec

__device__ __forceinline__ float dot4(float4 a, float4 b) {
    return a.x * b.x + a.y * b.y + a.z * b.z + a.w * b.w;
}
__device__ __forceinline__ float dot4v(floatv4 a, float4 b) {
    return a.x * b.x + a.y * b.y + a.z * b.z + a.w * b.w;
}

// ---------------- Kernel A: scores[b,s] = dot(hidden[b,s,:], w_align[H:2H]) ---
// Per-wave code identical to round-4 (the fastest A measured); grouped 16
// waves/block (8192 blocks) to cut dispatch churn. hidden via nontemporal
// loads (zero reuse -> don't pollute L2/L3). Invalid rows -> NEGV sentinel.
__global__ __launch_bounds__(1024) void scores_kernel(
        const float* __restrict__ hidden,
        const float* __restrict__ token_mask,
        const float* __restrict__ w_align,
        float* __restrict__ scores) {
    int row = blockIdx.x * 16 + (threadIdx.x >> 6);  // 16 waves per block
    int lane = threadIdx.x & 63;
    float m = token_mask[(size_t)row * HH];          // broadcast scalar per row
    if (m == 0.0f) {
        if (lane == 0) scores[row] = NEGV;
        return;
    }
    const float* hrow = hidden + (size_t)row * HH;
    const float* w2 = w_align + HH;
    float acc = 0.f;
#pragma unroll
    for (int r = 0; r < 3; ++r) {
        int idx = r * 256 + lane * 4;
        floatv4 h = __builtin_nontemporal_load(
            reinterpret_cast<const floatv4*>(hrow + idx));
        float4 w = *reinterpret_cast<const float4*>(w2 + idx);
        acc += dot4v(h, w);
    }
#pragma unroll
    for (int off = 32; off >= 1; off >>= 1) acc += __shfl_xor(acc, off);
    if (lane == 0) scores[row] = acc;
}

// ---------------- Kernel B: one block per batch row ---------------------------
// 64 blocks x 768 threads (12 waves). Wave 1 computes dotP (cold pooled_tokens
// load) CONCURRENTLY with wave 0's score loads; handoff via LDS + one barrier.
// Wave 0: Newton tau in registers, probs write, ballot-compaction into LDS.
// Barrier. All 12 waves gather pooled[b,h], 8 support rows in flight.
__global__ __launch_bounds__(768, 1) void tau_pool_kernel(
        const float* __restrict__ hidden,
        const float* __restrict__ pooled_tokens,
        const float* __restrict__ w_align,
        const float* __restrict__ b_align,
        const float* __restrict__ scores,
        float* __restrict__ out) {
    __shared__ int   s_idx[SS];
    __shared__ float s_p[SS];
    __shared__ int   s_cnt;
    __shared__ float s_dp;

    const int b = blockIdx.x;
    const int t = threadIdx.x;
    const int lane = t & 63;
    const int wv = t >> 6;

    // --- phase 0 (overlapped cold loads) ---
    float4 sv[8];
    if (wv == 0) {
        const float* sc = scores + b * SS;
#pragma unroll
        for (int i = 0; i < 8; ++i)
            sv[i] = *reinterpret_cast<const float4*>(sc + i * 256 + lane * 4);
    } else if (wv == 1) {
        const float* pt = pooled_tokens + b * HH;
        float dp = 0.f;
#pragma unroll
        for (int i = 0; i < 3; ++i) {
            int idx = i * 256 + lane * 4;
            float4 a = *reinterpret_cast<const float4*>(pt + idx);
            float4 w = *reinterpret_cast<const float4*>(w_align + idx);
            dp += dot4(a, w);
        }
#pragma unroll
        for (int off = 32; off >= 1; off >>= 1) dp += __shfl_xor(dp, off);
        if (lane == 0) s_dp = dp + b_align[0];
    }
    __syncthreads();

    if (wv == 0) {
        const float dp = s_dp;

        // --- z from scores (NEGV sentinel == invalid) ---
        float z[32];
#pragma unroll
        for (int i = 0; i < 8; ++i) {
            z[i * 4 + 0] = (sv[i].x > -1e29f) ? sv[i].x + dp : NEGV;
            z[i * 4 + 1] = (sv[i].y > -1e29f) ? sv[i].y + dp : NEGV;
            z[i * 4 + 2] = (sv[i].z > -1e29f) ? sv[i].z + dp : NEGV;
            z[i * 4 + 3] = (sv[i].w > -1e29f) ? sv[i].w + dp : NEGV;
        }

        // --- zmax over valid (invalid ~ -1e30 never wins; >=16 valid) ---
        float mx = z[0];
#pragma unroll
        for (int i = 1; i < 32; ++i) mx = fmaxf(mx, z[i]);
#pragma unroll
        for (int off = 32; off >= 1; off >>= 1) mx = fmaxf(mx, __shfl_xor(mx, off));
#pragma unroll
        for (int i = 0; i < 32; ++i) z[i] -= mx;

        // --- Newton on f(tau) = sum(max(z-tau,0)) - 1 ---
        // tau0=-1: f>=0; monotone increase, active set monotone shrink, exact
        // on stabilization. Count never 0 (max element stays active).
        float tau = -1.0f;
#pragma unroll 1
        for (int it = 0; it < 50; ++it) {
            float a = 0.f, c = 0.f;
#pragma unroll
            for (int i = 0; i < 32; ++i) {
                bool g = z[i] > tau;
                a += g ? z[i] : 0.f;
                c += g ? 1.f : 0.f;
            }
#pragma unroll
            for (int off = 32; off >= 1; off >>= 1) {
                a += __shfl_xor(a, off);
                c += __shfl_xor(c, off);
            }
            float tn = (a - 1.f + LAM) / c;
            if (tn == tau) break;      // wave-uniform
            tau = tn;
        }

        // --- probs: coalesced float4 write, then ballot-compaction into LDS ---
        const float inv = 1.f / (1.f - LAM);
        float p[32];
#pragma unroll
        for (int i = 0; i < 32; ++i) p[i] = fmaxf((z[i] - tau) * inv, 0.f);
        float* po = out + BB * HH + b * SS;
#pragma unroll
        for (int i = 0; i < 8; ++i) {
            float4 v = make_float4(p[i * 4 + 0], p[i * 4 + 1], p[i * 4 + 2], p[i * 4 + 3]);
            *reinterpret_cast<float4*>(po + i * 256 + lane * 4) = v;
        }

        int cnt = 0;
#pragma unroll
        for (int i = 0; i < 8; ++i) {
#pragma unroll
            for (int c = 0; c < 4; ++c) {
                float pv = p[i * 4 + c];
                unsigned long long m = __ballot(pv > 0.f);
                if (pv > 0.f) {
                    int pos = cnt + (int)__popcll(m & ((1ull << lane) - 1ull));
                    s_idx[pos] = i * 256 + lane * 4 + c;
                    s_p[pos] = pv;
                }
                cnt += (int)__popcll(m);
            }
        }
        if (lane == 0) s_cnt = cnt;
    }
    __syncthreads();

    // --- pooled[b,h]: all 12 waves, thread t <-> column h=t, 8 rows in flight -
    const int cnt = s_cnt;
    const float* hb = hidden + (size_t)b * SS * HH;
    float acc = 0.f;
#pragma unroll 1
    for (int j = 0; j < cnt; j += 8) {
        float hv[8], pv[8];
#pragma unroll
        for (int k = 0; k < 8; ++k) {
            int jj = j + k;
            int idx = (jj < cnt) ? s_idx[jj] : 0;
            pv[k] = (jj < cnt) ? s_p[jj] : 0.f;
            hv[k] = hb[(size_t)idx * HH + t];
        }
#pragma unroll
        for (int k = 0; k < 8; ++k) acc += pv[k] * hv[k];
    }
    out[b * HH + t] = acc;
}

extern "C" void kernel_launch(void* const* d_in, const int* in_sizes, int n_in,
                              void* d_out, int out_size, void* d_ws, size_t ws_size,
                              hipStream_t stream) {
    const float* hidden        = (const float*)d_in[0];
    const float* token_mask    = (const float*)d_in[1];
    const float* pooled_tokens = (const float*)d_in[2];
    const float* w_align       = (const float*)d_in[3];
    const float* b_align       = (const float*)d_in[4];
    float* out = (float*)d_out;

    // scratch for raw scores [B,S]; fall back to the probs region of d_out
    // (wave 0 of B reads the full row into registers before overwriting) if
    // ws is too small
    float* scores_ws;
    if (ws_size >= (size_t)BB * SS * sizeof(float)) {
        scores_ws = (float*)d_ws;
    } else {
        scores_ws = out + BB * HH;
    }

    scores_kernel<<<dim3((BB * SS) / 16), dim3(1024), 0, stream>>>(
        hidden, token_mask, w_align, scores_ws);

    tau_pool_kernel<<<dim3(BB), dim3(768), 0, stream>>>(
        hidden, pooled_tokens, w_align, b_align, scores_ws, out);
}

// Round 11
// 47.939 us; speedup vs baseline: 3.0951x; 1.1447x over previous
//
#include <hip/hip_runtime.h>
#include <hip/hip_bf16.h>
#include <cstdint>
#include <cstddef>

#define BB 64
#define SS 2048
#define HH 768
#define LAM 0.0f
#define NEGV -1e30f

__device__ __forceinline__ float dot4(float4 a, float4 b) {
    return a.x * b.x + a.y * b.y + a.z * b.z + a.w * b.w;
}

// ---------------- Kernel A: scores[b,s] = dot(hidden[b,s,:], w_align[H:2H]) ---
// ROUND-4 VERBATIM — empirically the fastest A (33.5 us, ~96% of achieved
// stream BW). One wave per (b,s) row, 4 waves per 256-thread block; validity
// from one wave-uniform mask probe; invalid rows write NEGV sentinel.
// Rounds 5/6/7/10 tried lens-probes, wide unrolls, persistence, 1024-thread
// blocks, nontemporal loads: ALL regressed or neutral. Do not touch.
__global__ void scores_kernel(const float* __restrict__ hidden,
                              const float* __restrict__ token_mask,
                              const float* __restrict__ w_align,
                              float* __restrict__ scores) {
    int row = blockIdx.x * 4 + (threadIdx.x >> 6);   // 4 waves per block
    int lane = threadIdx.x & 63;
    float m = token_mask[(size_t)row * HH];          // broadcast scalar per row
    if (m == 0.0f) {
        if (lane == 0) scores[row] = NEGV;
        return;
    }
    const float* hrow = hidden + (size_t)row * HH;
    const float* w2 = w_align + HH;
    float acc = 0.f;
#pragma unroll
    for (int r = 0; r < 3; ++r) {
        int idx = r * 256 + lane * 4;
        float4 h = *reinterpret_cast<const float4*>(hrow + idx);
        float4 w = *reinterpret_cast<const float4*>(w2 + idx);
        acc += h.x * w.x + h.y * w.y + h.z * w.z + h.w * w.w;
    }
#pragma unroll
    for (int off = 32; off >= 1; off >>= 1) acc += __shfl_xor(acc, off);
    if (lane == 0) scores[row] = acc;
}

// ---------------- Kernel B: one block per batch row ---------------------------
// 64 blocks x 768 threads (12 waves). Wave 1 computes dotP (cold pooled_tokens
// load) CONCURRENTLY with wave 0's score loads; handoff via LDS + one barrier.
// Wave 0: Newton tau in registers, probs write, ballot-compaction into LDS.
// Barrier. All 12 waves gather pooled[b,h], 8 support rows in flight.
__global__ __launch_bounds__(768, 1) void tau_pool_kernel(
        const float* __restrict__ hidden,
        const float* __restrict__ pooled_tokens,
        const float* __restrict__ w_align,
        const float* __restrict__ b_align,
        const float* __restrict__ scores,
        float* __restrict__ out) {
    __shared__ int   s_idx[SS];
    __shared__ float s_p[SS];
    __shared__ int   s_cnt;
    __shared__ float s_dp;

    const int b = blockIdx.x;
    const int t = threadIdx.x;
    const int lane = t & 63;
    const int wv = t >> 6;

    // --- phase 0 (overlapped cold loads) ---
    float4 sv[8];
    if (wv == 0) {
        const float* sc = scores + b * SS;
#pragma unroll
        for (int i = 0; i < 8; ++i)
            sv[i] = *reinterpret_cast<const float4*>(sc + i * 256 + lane * 4);
    } else if (wv == 1) {
        const float* pt = pooled_tokens + b * HH;
        float dp = 0.f;
#pragma unroll
        for (int i = 0; i < 3; ++i) {
            int idx = i * 256 + lane * 4;
            float4 a = *reinterpret_cast<const float4*>(pt + idx);
            float4 w = *reinterpret_cast<const float4*>(w_align + idx);
            dp += dot4(a, w);
        }
#pragma unroll
        for (int off = 32; off >= 1; off >>= 1) dp += __shfl_xor(dp, off);
        if (lane == 0) s_dp = dp + b_align[0];
    }
    __syncthreads();

    if (wv == 0) {
        const float dp = s_dp;

        // --- z from scores (NEGV sentinel == invalid) ---
        float z[32];
#pragma unroll
        for (int i = 0; i < 8; ++i) {
            z[i * 4 + 0] = (sv[i].x > -1e29f) ? sv[i].x + dp : NEGV;
            z[i * 4 + 1] = (sv[i].y > -1e29f) ? sv[i].y + dp : NEGV;
            z[i * 4 + 2] = (sv[i].z > -1e29f) ? sv[i].z + dp : NEGV;
            z[i * 4 + 3] = (sv[i].w > -1e29f) ? sv[i].w + dp : NEGV;
        }

        // --- zmax over valid (invalid ~ -1e30 never wins; >=16 valid) ---
        float mx = z[0];
#pragma unroll
        for (int i = 1; i < 32; ++i) mx = fmaxf(mx, z[i]);
#pragma unroll
        for (int off = 32; off >= 1; off >>= 1) mx = fmaxf(mx, __shfl_xor(mx, off));
#pragma unroll
        for (int i = 0; i < 32; ++i) z[i] -= mx;

        // --- Newton on f(tau) = sum(max(z-tau,0)) - 1 ---
        // tau0=-1: f>=0; monotone increase, active set monotone shrink, exact
        // on stabilization. Count never 0 (max element stays active).
        float tau = -1.0f;
#pragma unroll 1
        for (int it = 0; it < 50; ++it) {
            float a = 0.f, c = 0.f;
#pragma unroll
            for (int i = 0; i < 32; ++i) {
                bool g = z[i] > tau;
                a += g ? z[i] : 0.f;
                c += g ? 1.f : 0.f;
            }
#pragma unroll
            for (int off = 32; off >= 1; off >>= 1) {
                a += __shfl_xor(a, off);
                c += __shfl_xor(c, off);
            }
            float tn = (a - 1.f + LAM) / c;
            if (tn == tau) break;      // wave-uniform
            tau = tn;
        }

        // --- probs: coalesced float4 write, then ballot-compaction into LDS ---
        const float inv = 1.f / (1.f - LAM);
        float p[32];
#pragma unroll
        for (int i = 0; i < 32; ++i) p[i] = fmaxf((z[i] - tau) * inv, 0.f);
        float* po = out + BB * HH + b * SS;
#pragma unroll
        for (int i = 0; i < 8; ++i) {
            float4 v = make_float4(p[i * 4 + 0], p[i * 4 + 1], p[i * 4 + 2], p[i * 4 + 3]);
            *reinterpret_cast<float4*>(po + i * 256 + lane * 4) = v;
        }

        int cnt = 0;
#pragma unroll
        for (int i = 0; i < 8; ++i) {
#pragma unroll
            for (int c = 0; c < 4; ++c) {
                float pv = p[i * 4 + c];
                unsigned long long m = __ballot(pv > 0.f);
                if (pv > 0.f) {
                    int pos = cnt + (int)__popcll(m & ((1ull << lane) - 1ull));
                    s_idx[pos] = i * 256 + lane * 4 + c;
                    s_p[pos] = pv;
                }
                cnt += (int)__popcll(m);
            }
        }
        if (lane == 0) s_cnt = cnt;
    }
    __syncthreads();

    // --- pooled[b,h]: all 12 waves, thread t <-> column h=t, 8 rows in flight -
    const int cnt = s_cnt;
    const float* hb = hidden + (size_t)b * SS * HH;
    float acc = 0.f;
#pragma unroll 1
    for (int j = 0; j < cnt; j += 8) {
        float hv[8], pv[8];
#pragma unroll
        for (int k = 0; k < 8; ++k) {
            int jj = j + k;
            int idx = (jj < cnt) ? s_idx[jj] : 0;
            pv[k] = (jj < cnt) ? s_p[jj] : 0.f;
            hv[k] = hb[(size_t)idx * HH + t];
        }
#pragma unroll
        for (int k = 0; k < 8; ++k) acc += pv[k] * hv[k];
    }
    out[b * HH + t] = acc;
}

extern "C" void kernel_launch(void* const* d_in, const int* in_sizes, int n_in,
                              void* d_out, int out_size, void* d_ws, size_t ws_size,
                              hipStream_t stream) {
    const float* hidden        = (const float*)d_in[0];
    const float* token_mask    = (const float*)d_in[1];
    const float* pooled_tokens = (const float*)d_in[2];
    const float* w_align       = (const float*)d_in[3];
    const float* b_align       = (const float*)d_in[4];
    float* out = (float*)d_out;

    // scratch for raw scores [B,S]; fall back to the probs region of d_out
    // (wave 0 of B reads the full row into registers before overwriting) if
    // ws is too small
    float* scores_ws;
    if (ws_size >= (size_t)BB * SS * sizeof(float)) {
        scores_ws = (float*)d_ws;
    } else {
        scores_ws = out + BB * HH;
    }

    scores_kernel<<<dim3((BB * SS) / 4), dim3(256), 0, stream>>>(
        hidden, token_mask, w_align, scores_ws);

    tau_pool_kernel<<<dim3(BB), dim3(768), 0, stream>>>(
        hidden, pooled_tokens, w_align, b_align, scores_ws, out);
}